// Round 9
// baseline (293.733 us; speedup 1.0000x reference)
//
#include <hip/hip_runtime.h>
#include <hip/hip_bf16.h>
#include <math.h>

#define N_   1024
#define S_   256
#define D_   256
#define C_   256
#define R_   64
#define CLS_ 1000
#define INV16 0.0625f

typedef unsigned short ushortT;
typedef unsigned int uint32;
typedef short bf8 __attribute__((ext_vector_type(8)));
typedef float f4 __attribute__((ext_vector_type(4)));

static __device__ __forceinline__ float bf2f(uint32 u){
  return __uint_as_float(u << 16);
}
static __device__ __forceinline__ ushortT f2bf(float f){
  uint32 x = __float_as_uint(f);
  uint32 r = x + 0x7FFFu + ((x >> 16) & 1u);
  return (ushortT)(r >> 16);
}
static __device__ __forceinline__ uint32 packbf(float a, float b){
  return ((uint32)f2bf(b) << 16) | (uint32)f2bf(a);
}
static __device__ __forceinline__ float wred_max(float v){
  for (int o = 32; o; o >>= 1) v = fmaxf(v, __shfl_xor(v, o));
  return v;
}
static __device__ __forceinline__ float wred_sum(float v){
  for (int o = 32; o; o >>= 1) v += __shfl_xor(v, o);
  return v;
}
// swizzled byte offset inside a [rows][256]-bf16 LDS tile (row stride 512B)
static __device__ __forceinline__ int swz(int row, int colbyte){
  return row*512 + ((colbyte & ~15) ^ ((row & 7) << 4)) + (colbyte & 15);
}
// fragment-ready packed index for a [rows x 256] matrix, 16-row frags, K-step 32
static __device__ __forceinline__ int pkidx(int row, int col, int nfrag){
  int ks = col >> 5, hi = (col >> 3) & 3, e = col & 7;
  int frag = row >> 4, l15p = row & 15;
  return ((ks*nfrag + frag)*64 + hi*16 + l15p)*8 + e;
}

// ---------------- K0: bf16 weight prep (frag-packed A1cat, Wcr) ---------------
__global__ __launch_bounds__(256) void k0(const float* __restrict__ cb,
    const float* __restrict__ rcb, const float* __restrict__ Wc,
    const float* __restrict__ Wr, ushortT* __restrict__ a1pk,
    ushortT* __restrict__ Wcr_bf)
{
  int t = blockIdx.x*256 + threadIdx.x;
  int stride = gridDim.x*256;
  for (int e = t; e < (C_ + R_)*D_; e += stride){
    int row = e >> 8, col = e & 255;
    float v = (row < C_) ? cb[e] : rcb[e - C_*D_];
    a1pk[pkidx(row, col, 20)] = f2bf(v);
  }
  for (int e = t; e < CLS_*D_; e += stride) Wcr_bf[e] = f2bf(Wc[e]);
  for (int e = t; e < D_*D_; e += stride)  Wcr_bf[CLS_*D_ + e] = f2bf(Wr[e]);
  for (int e = t; e < 24*D_; e += stride)  Wcr_bf[1256*D_ + e] = 0;
}

// ---------------- K0m: M = cb @ rcb^T -> MT_f32 [r][c] + frag-packed bf16 -----
__global__ __launch_bounds__(256) void k0m(const float* __restrict__ cb,
    const float* __restrict__ rcb, float* __restrict__ MT_f32,
    ushortT* __restrict__ mtpk)
{
  __shared__ float rl[D_];
  int r = blockIdx.x;        // 0..63
  int t = threadIdx.x;       // c = 0..255
  rl[t] = rcb[r*D_ + t];
  __syncthreads();
  float acc = 0.f;
  const float* crow = cb + t*D_;
  #pragma unroll 8
  for (int k = 0; k < D_; k += 4){
    float4 w = *(const float4*)(crow + k);
    acc += w.x*rl[k] + w.y*rl[k+1] + w.z*rl[k+2] + w.w*rl[k+3];
  }
  MT_f32[r*C_ + t] = acc;
  mtpk[pkidx(r, t, 4)] = f2bf(acc);
}

// ---------------- K1: per-query pass ------------------------------------------
__global__ __launch_bounds__(256) void k1(const float* __restrict__ q,
    const float* __restrict__ cb, const float* __restrict__ rcb,
    const float* __restrict__ Wq, const float* __restrict__ MT_f32,
    float* __restrict__ cw_ws, float* __restrict__ rcw_ws)
{
  __shared__ float qv[D_], qp[D_], red[8], redB[8], cwl[C_];
  int n = blockIdx.x, t = threadIdx.x;
  qv[t] = q[n*D_ + t];
  __syncthreads();
  {
    float acc = 0.f;
    const float* wrow = Wq + t*D_;
    #pragma unroll 8
    for (int k = 0; k < D_; k += 4){
      float4 w = *(const float4*)(wrow + k);
      acc += qv[k]*w.x + qv[k+1]*w.y + qv[k+2]*w.z + qv[k+3]*w.w;
    }
    qp[t] = acc;
  }
  __syncthreads();
  float L = 0.f;
  {
    const float* crow = cb + t*D_;
    #pragma unroll 8
    for (int k = 0; k < D_; k += 4){
      float4 w = *(const float4*)(crow + k);
      L += qp[k]*w.x + qp[k+1]*w.y + qp[k+2]*w.z + qp[k+3]*w.w;
    }
    L *= INV16;
  }
  float m = wred_max(L);
  if ((t & 63) == 0) red[t >> 6] = m;
  __syncthreads();
  m = fmaxf(fmaxf(red[0], red[1]), fmaxf(red[2], red[3]));
  float e = __expf(L - m);
  float s = wred_sum(e);
  if ((t & 63) == 0) redB[t >> 6] = s;
  __syncthreads();
  s = redB[0] + redB[1] + redB[2] + redB[3];
  float w = e / s;
  cwl[t] = w;
  cw_ws[n*C_ + t] = w;
  __syncthreads();
  if (t < R_){
    float qdot = 0.f, mdot = 0.f;
    const float* rrow = rcb + t*D_;
    const float* mrow = MT_f32 + t*C_;
    #pragma unroll 8
    for (int k = 0; k < D_; k += 4){
      float4 wv = *(const float4*)(rrow + k);
      qdot += qp[k]*wv.x + qp[k+1]*wv.y + qp[k+2]*wv.z + qp[k+3]*wv.w;
      float4 mv = *(const float4*)(mrow + k);
      mdot += cwl[k]*mv.x + cwl[k+1]*mv.y + cwl[k+2]*mv.z + cwl[k+3]*mv.w;
    }
    float Lr = (qdot - mdot) * INV16;
    float mr = wred_max(Lr);
    float er = __expf(Lr - mr);
    float sr = wred_sum(er);
    rcw_ws[n*R_ + t] = er / sr;
  }
}

// ---------------- K2: BARRIER-FREE fused pass ---------------------------------
// grid = N_*2 blocks x 256 thr; each WAVE independently owns (n, 32-s stripe).
// K frags direct-from-global fp32 (held in regs as bf16); A1/MT streamed from
// L2 with depth-1 prefetch; W via wave-private LDS slice (lgkmcnt-only sync);
// softmaxes fully wave-local.
__global__ __launch_bounds__(256) void k2(const float* __restrict__ Kt,
    const float* __restrict__ Vt, const ushortT* __restrict__ a1pk,
    const ushortT* __restrict__ mtpk, const float* __restrict__ cw_ws,
    const float* __restrict__ rcw_ws, const float* __restrict__ rlogit,
    float* __restrict__ sum_ws, float* __restrict__ out_ew)
{
  __shared__ __align__(16) ushortT Wl[4][32][264];   // 67584 B, wave-private slices

  int bx  = blockIdx.x;
  int n   = bx >> 1;
  int tid = threadIdx.x;
  int lane = tid & 63, w = tid >> 6;
  int l15 = lane & 15, l4 = lane >> 4;
  int s0w = (bx & 1)*128 + w*32;          // this wave's absolute s base
  float gate  = 1.f / (1.f + __expf(-rlogit[0]));
  float inv1g = 1.f / (1.f + gate);

  const float* Kn = Kt + (size_t)n*S_*D_ + (size_t)s0w*D_;
  const float* Vn = Vt + (size_t)n*S_*D_ + (size_t)s0w*D_;

  // ---- K preload: 16 B-frags (2 s-halves x 8 ks), fp32 global -> bf16 regs ----
  bf8 kreg[16];
  #pragma unroll
  for (int sh = 0; sh < 2; sh++)
    #pragma unroll
    for (int ks = 0; ks < 8; ks++){
      const float* kp = Kn + (size_t)(sh*16 + l15)*D_ + ks*32 + l4*8;
      float4 a = *(const float4*)kp;
      float4 b = *(const float4*)(kp + 4);
      union { bf8 v; uint32 u[4]; } x;
      x.u[0] = packbf(a.x, a.y); x.u[1] = packbf(a.z, a.w);
      x.u[2] = packbf(b.x, b.y); x.u[3] = packbf(b.z, b.w);
      kreg[sh*8 + ks] = x.v;
    }

  // ---- GEMM1': A1cat(320 rows) x K^T -> acc[20][2]; depth-1 A prefetch ------
  const ushortT* a1w = a1pk + (size_t)lane*8;
  bf8 bnx[20];
  #pragma unroll
  for (int f = 0; f < 20; f++)
    bnx[f] = *(const bf8*)(a1w + (size_t)f*512);
  f4 acc[20][2];
  #pragma unroll
  for (int f = 0; f < 20; f++){ acc[f][0] = (f4)0.f; acc[f][1] = (f4)0.f; }
  #pragma unroll
  for (int ks = 0; ks < 8; ks++){
    #pragma unroll
    for (int f = 0; f < 20; f++){
      bf8 a = bnx[f];
      if (ks < 7) bnx[f] = *(const bf8*)(a1w + (size_t)((ks+1)*20 + f)*512);
      acc[f][0] = __builtin_amdgcn_mfma_f32_16x16x32_bf16(a, kreg[ks],     acc[f][0], 0, 0, 0);
      acc[f][1] = __builtin_amdgcn_mfma_f32_16x16x32_bf16(a, kreg[8 + ks], acc[f][1], 0, 0, 0);
    }
  }

  // ---- softmax over c: exp in place, write raw exp to wave LDS slice --------
  float4 cwv[16];
  #pragma unroll
  for (int f = 0; f < 16; f++)
    cwv[f] = *(const float4*)(cw_ws + n*C_ + f*16 + l4*4);

  float se[2] = {0.f, 0.f};
  #pragma unroll
  for (int f = 0; f < 16; f++){
    #pragma unroll
    for (int sh = 0; sh < 2; sh++){
      float e0 = __expf(acc[f][sh][0] * INV16);
      float e1 = __expf(acc[f][sh][1] * INV16);
      float e2 = __expf(acc[f][sh][2] * INV16);
      float e3 = __expf(acc[f][sh][3] * INV16);
      acc[f][sh][0] = e0; acc[f][sh][1] = e1;
      acc[f][sh][2] = e2; acc[f][sh][3] = e3;
      se[sh] += (e0 + e1) + (e2 + e3);
      ushortT* basep = &Wl[w][sh*16 + l15][f*16 + l4*4];
      *(uint32*)(basep)     = packbf(e0, e1);
      *(uint32*)(basep + 2) = packbf(e2, e3);
    }
  }
  float sb[2] = {0.f, 0.f};
  #pragma unroll
  for (int f = 0; f < 16; f++)
    #pragma unroll
    for (int sh = 0; sh < 2; sh++){
      sb[sh] += acc[f][sh][0]*cwv[f].x + acc[f][sh][1]*cwv[f].y
              + acc[f][sh][2]*cwv[f].z + acc[f][sh][3]*cwv[f].w;
    }
  #pragma unroll
  for (int sh = 0; sh < 2; sh++){
    se[sh] += __shfl_xor(se[sh], 16); se[sh] += __shfl_xor(se[sh], 32);
    sb[sh] += __shfl_xor(sb[sh], 16); sb[sh] += __shfl_xor(sb[sh], 32);
  }
  float rcpS0 = 1.f / se[0], rcpS1 = 1.f / se[1];
  float bw0 = sb[0] * rcpS0, bw1 = sb[1] * rcpS1;

  // ---- WM: MT(64 r) x Wexp^T -> wm[4][2]; MT depth-1 prefetch from L2 -------
  bf8 mnx[4];
  #pragma unroll
  for (int fr = 0; fr < 4; fr++)
    mnx[fr] = *(const bf8*)(mtpk + (size_t)(fr*64 + lane)*8);
  f4 wm[4][2];
  #pragma unroll
  for (int fr = 0; fr < 4; fr++){ wm[fr][0] = (f4)0.f; wm[fr][1] = (f4)0.f; }
  #pragma unroll
  for (int ks = 0; ks < 8; ks++){
    bf8 wb0 = *(const bf8*)(&Wl[w][     l15][ks*32 + l4*8]);
    bf8 wb1 = *(const bf8*)(&Wl[w][16 + l15][ks*32 + l4*8]);
    #pragma unroll
    for (int fr = 0; fr < 4; fr++){
      bf8 a = mnx[fr];
      if (ks < 7) mnx[fr] = *(const bf8*)(mtpk + (size_t)(((ks+1)*4 + fr)*64 + lane)*8);
      wm[fr][0] = __builtin_amdgcn_mfma_f32_16x16x32_bf16(a, wb0, wm[fr][0], 0, 0, 0);
      wm[fr][1] = __builtin_amdgcn_mfma_f32_16x16x32_bf16(a, wb1, wm[fr][1], 0, 0, 0);
    }
  }

  // ---- softmax over r: l3 = (acc_rcb - wm*rcpS)/16, wave-local --------------
  float4 rcwv[4];
  #pragma unroll
  for (int fr = 0; fr < 4; fr++)
    rcwv[fr] = *(const float4*)(rcw_ws + n*R_ + fr*16 + l4*4);
  float se3[2] = {0.f, 0.f}, sc3[2] = {0.f, 0.f};
  #pragma unroll
  for (int fr = 0; fr < 4; fr++)
    #pragma unroll
    for (int sh = 0; sh < 2; sh++){
      float rc = sh ? rcpS1 : rcpS0;
      float e0 = __expf((acc[16+fr][sh][0] - wm[fr][sh][0]*rc) * INV16);
      float e1 = __expf((acc[16+fr][sh][1] - wm[fr][sh][1]*rc) * INV16);
      float e2 = __expf((acc[16+fr][sh][2] - wm[fr][sh][2]*rc) * INV16);
      float e3 = __expf((acc[16+fr][sh][3] - wm[fr][sh][3]*rc) * INV16);
      se3[sh] += (e0 + e1) + (e2 + e3);
      sc3[sh] += e0*rcwv[fr].x + e1*rcwv[fr].y + e2*rcwv[fr].z + e3*rcwv[fr].w;
    }
  #pragma unroll
  for (int sh = 0; sh < 2; sh++){
    se3[sh] += __shfl_xor(se3[sh], 16); se3[sh] += __shfl_xor(se3[sh], 32);
    sc3[sh] += __shfl_xor(sc3[sh], 16); sc3[sh] += __shfl_xor(sc3[sh], 32);
  }
  float comb0 = bw0 + gate * (sc3[0] / se3[0]);
  float comb1 = bw1 + gate * (sc3[1] / se3[1]);
  if (l4 == 0){
    out_ew[n*S_ + s0w +      l15] = comb0 * inv1g;
    out_ew[n*S_ + s0w + 16 + l15] = comb1 * inv1g;
  }

  // ---- summary: 32 s-rows of V, comb via in-wave shfl; direct atomics -------
  float4 sacc = {0.f, 0.f, 0.f, 0.f};
  #pragma unroll
  for (int jb = 0; jb < 4; jb++){
    float4 vb[8];
    #pragma unroll
    for (int j = 0; j < 8; j++)
      vb[j] = *(const float4*)(Vn + (size_t)(jb*8 + j)*D_ + lane*4);
    #pragma unroll
    for (int j = 0; j < 8; j++){
      int s = jb*8 + j;
      float cj = __shfl(s < 16 ? comb0 : comb1, s & 15);
      sacc.x = fmaf(cj, vb[j].x, sacc.x); sacc.y = fmaf(cj, vb[j].y, sacc.y);
      sacc.z = fmaf(cj, vb[j].z, sacc.z); sacc.w = fmaf(cj, vb[j].w, sacc.w);
    }
  }
  float* dst = sum_ws + (size_t)n*D_ + lane*4;
  atomicAdd(dst + 0, sacc.x);
  atomicAdd(dst + 1, sacc.y);
  atomicAdd(dst + 2, sacc.z);
  atomicAdd(dst + 3, sacc.w);
}

// ---------------- K3: readout GEMM (MFMA, bf16) --------------------------------
__global__ __launch_bounds__(256) void k3(const float* __restrict__ sum_ws,
    const ushortT* __restrict__ Wcr_bf, const float* __restrict__ bc,
    const float* __restrict__ br, float* __restrict__ out)
{
  __shared__ __align__(16) ushortT Stile[64*256];   // 32 KB swizzled bf16 summary tile
  int bx = blockIdx.x;
  int ot = bx >> 4;           // 0..19 output tile (64 wide over [Wc;Wr;pad])
  int nt = bx & 15;           // 0..15 n tile (64 rows)
  int tid = threadIdx.x;
  int lane = tid & 63, wid = tid >> 6;
  int l15 = lane & 15, l4 = lane >> 4;

  const float* Sp = sum_ws + (size_t)nt*64*D_;
  #pragma unroll
  for (int j = 0; j < 8; j++){
    int ch = tid + j*256;
    int row = ch >> 5, blk = ch & 31;
    const float* src = Sp + row*D_ + blk*8;
    float4 a = *(const float4*)src;
    float4 b = *(const float4*)(src + 4);
    uint4 wv = {packbf(a.x,a.y), packbf(a.z,a.w), packbf(b.x,b.y), packbf(b.z,b.w)};
    *(uint4*)((char*)Stile + swz(row, blk*16)) = wv;
  }
  __syncthreads();

  int o0 = ot*64 + wid*16;
  const ushortT* Ap = Wcr_bf + (size_t)(o0 + l15)*D_ + l4*8;
  f4 acc[4];
  #pragma unroll
  for (int j = 0; j < 4; j++) acc[j] = (f4)0.f;
  #pragma unroll
  for (int k = 0; k < 8; k++){
    bf8 a = *(const bf8*)(Ap + k*32);
    #pragma unroll
    for (int nj = 0; nj < 4; nj++){
      bf8 b = *(const bf8*)((const char*)Stile + swz(nj*16 + l15, k*64 + l4*16));
      acc[nj] = __builtin_amdgcn_mfma_f32_16x16x32_bf16(a, b, acc[nj], 0, 0, 0);
    }
  }
  int obase = o0 + l4*4;
  if (obase < 1256){
    float4 bias;
    if (obase < CLS_) bias = *(const float4*)(bc + obase);
    else              bias = *(const float4*)(br + (obase - CLS_));
    #pragma unroll
    for (int nj = 0; nj < 4; nj++){
      int nn = nt*64 + nj*16 + l15;
      float4 v = {acc[nj][0]+bias.x, acc[nj][1]+bias.y, acc[nj][2]+bias.z, acc[nj][3]+bias.w};
      if (obase < CLS_) *(float4*)(out + (size_t)nn*CLS_ + obase) = v;
      else              *(float4*)(out + (size_t)N_*CLS_ + (size_t)nn*D_ + (obase - CLS_)) = v;
    }
  }
}

extern "C" void kernel_launch(void* const* d_in, const int* in_sizes, int n_in,
                              void* d_out, int out_size, void* d_ws, size_t ws_size,
                              hipStream_t stream)
{
  const float* q    = (const float*)d_in[0];
  const float* Kt   = (const float*)d_in[1];
  const float* Vt   = (const float*)d_in[2];
  const float* cb   = (const float*)d_in[3];
  const float* rcb  = (const float*)d_in[4];
  const float* Wq   = (const float*)d_in[5];
  const float* rlg  = (const float*)d_in[6];
  const float* Wc   = (const float*)d_in[7];
  const float* bc   = (const float*)d_in[8];
  const float* Wr   = (const float*)d_in[9];
  const float* br   = (const float*)d_in[10];
  float* out = (float*)d_out;
  float* ws  = (float*)d_ws;

  float* cw_ws  = ws;                          // N*C floats
  float* rcw_ws = ws + 262144;                 // N*R
  float* sum_ws = ws + 327680;                 // N*D
  float* MT_f32 = ws + 589824;                 // R*C
  ushortT* a1pk   = (ushortT*)(ws + 606208);   // 320*D frag-packed
  ushortT* mtpk   = a1pk + (C_ + R_)*D_;       // R*C frag-packed
  ushortT* Wcr_bf = mtpk + R_*C_;              // 1280*D (Wc ; Wr ; zero pad)

  float* out_logits = out;
  float* out_ew     = out + (size_t)N_*CLS_ + (size_t)N_*D_;

  hipMemsetAsync(sum_ws, 0, (size_t)N_*D_*sizeof(float), stream);
  k0 <<<128,  256, 0, stream>>>(cb, rcb, Wc, Wr, a1pk, Wcr_bf);
  k0m<<<R_,   256, 0, stream>>>(cb, rcb, MT_f32, mtpk);
  k1 <<<N_,   256, 0, stream>>>(q, cb, rcb, Wq, MT_f32, cw_ws, rcw_ws);
  k2 <<<N_*2, 256, 0, stream>>>(Kt, Vt, a1pk, mtpk, cw_ws, rcw_ws, rlg,
                                sum_ws, out_ew);
  k3 <<<320,  256, 0, stream>>>(sum_ws, Wcr_bf, bc, br, out_logits);
}

// Round 10
// 234.446 us; speedup vs baseline: 1.2529x; 1.2529x over previous
//
#include <hip/hip_runtime.h>
#include <hip/hip_bf16.h>
#include <math.h>

#define N_   1024
#define S_   256
#define D_   256
#define C_   256
#define R_   64
#define CLS_ 1000
#define INV16 0.0625f

typedef unsigned short ushortT;
typedef unsigned int uint32;
typedef short bf8 __attribute__((ext_vector_type(8)));
typedef float f4 __attribute__((ext_vector_type(4)));

static __device__ __forceinline__ float bf2f(uint32 u){
  return __uint_as_float(u << 16);
}
static __device__ __forceinline__ ushortT f2bf(float f){
  uint32 x = __float_as_uint(f);
  uint32 r = x + 0x7FFFu + ((x >> 16) & 1u);
  return (ushortT)(r >> 16);
}
static __device__ __forceinline__ uint32 packbf(float a, float b){
  return ((uint32)f2bf(b) << 16) | (uint32)f2bf(a);
}
static __device__ __forceinline__ float wred_max(float v){
  for (int o = 32; o; o >>= 1) v = fmaxf(v, __shfl_xor(v, o));
  return v;
}
static __device__ __forceinline__ float wred_sum(float v){
  for (int o = 32; o; o >>= 1) v += __shfl_xor(v, o);
  return v;
}
// swizzled byte offset inside a [rows][256]-bf16 LDS tile (row stride 512B)
static __device__ __forceinline__ int swz(int row, int colbyte){
  return row*512 + ((colbyte & ~15) ^ ((row & 7) << 4)) + (colbyte & 15);
}
// fragment-ready packed index for a [rows x 256] matrix, 16-row frags, K-step 32
static __device__ __forceinline__ int pkidx(int row, int col, int nfrag){
  int ks = col >> 5, hi = (col >> 3) & 3, e = col & 7;
  int frag = row >> 4, l15p = row & 15;
  return ((ks*nfrag + frag)*64 + hi*16 + l15p)*8 + e;
}

// ---------------- K0: weight prep + MT = cb @ rcb^T ---------------------------
__global__ __launch_bounds__(256) void k0(const float* __restrict__ cb,
    const float* __restrict__ rcb, const float* __restrict__ Wc,
    const float* __restrict__ Wr, ushortT* __restrict__ a1pk,
    ushortT* __restrict__ Wcr_bf, float* __restrict__ MT_f32,
    ushortT* __restrict__ mtpk)
{
  __shared__ float rl[D_];
  int bid = blockIdx.x, t = threadIdx.x;
  int gtid = bid*256 + t;
  int stride = gridDim.x*256;
  for (int e = gtid; e < (C_ + R_)*D_; e += stride){
    int row = e >> 8, col = e & 255;
    float v = (row < C_) ? cb[e] : rcb[e - C_*D_];
    a1pk[pkidx(row, col, 20)] = f2bf(v);
  }
  for (int e = gtid; e < CLS_*D_; e += stride) Wcr_bf[e] = f2bf(Wc[e]);
  for (int e = gtid; e < D_*D_; e += stride)  Wcr_bf[CLS_*D_ + e] = f2bf(Wr[e]);
  for (int e = gtid; e < 24*D_; e += stride)  Wcr_bf[1256*D_ + e] = 0;

  if (bid < R_){
    rl[t] = rcb[bid*D_ + t];
    __syncthreads();
    float acc = 0.f;
    const float* crow = cb + t*D_;
    #pragma unroll 8
    for (int k = 0; k < D_; k += 4){
      float4 w = *(const float4*)(crow + k);
      acc += w.x*rl[k] + w.y*rl[k+1] + w.z*rl[k+2] + w.w*rl[k+3];
    }
    MT_f32[bid*C_ + t] = acc;
    mtpk[pkidx(bid, t, 4)] = f2bf(acc);
  }
}

// ---------------- K1: per-query pass, batched x4 ------------------------------
#define G4 4
__global__ __launch_bounds__(256) void k1(const float* __restrict__ q,
    const float* __restrict__ cb, const float* __restrict__ rcb,
    const float* __restrict__ Wq, const float* __restrict__ MT_f32,
    float* __restrict__ cw_ws, float* __restrict__ rcw_ws)
{
  __shared__ float qv[G4][D_], qp[G4][D_], cwl[G4][C_];
  __shared__ float redA[G4][4], redB2[G4][4];
  int n0 = blockIdx.x*G4, t = threadIdx.x;
  #pragma unroll
  for (int g = 0; g < G4; g++) qv[g][t] = q[(n0+g)*D_ + t];
  __syncthreads();
  // q_proj (thread t = output dim)
  {
    float acc[G4] = {0.f,0.f,0.f,0.f};
    const float* wrow = Wq + t*D_;
    #pragma unroll 4
    for (int k = 0; k < D_; k += 4){
      float4 w = *(const float4*)(wrow + k);
      #pragma unroll
      for (int g = 0; g < G4; g++)
        acc[g] += qv[g][k]*w.x + qv[g][k+1]*w.y + qv[g][k+2]*w.z + qv[g][k+3]*w.w;
    }
    #pragma unroll
    for (int g = 0; g < G4; g++) qp[g][t] = acc[g];
  }
  __syncthreads();
  // cw logits (thread t = c)
  float L[G4] = {0.f,0.f,0.f,0.f};
  {
    const float* crow = cb + t*D_;
    #pragma unroll 4
    for (int k = 0; k < D_; k += 4){
      float4 w = *(const float4*)(crow + k);
      #pragma unroll
      for (int g = 0; g < G4; g++)
        L[g] += qp[g][k]*w.x + qp[g][k+1]*w.y + qp[g][k+2]*w.z + qp[g][k+3]*w.w;
    }
  }
  float m[G4], e[G4], s[G4];
  #pragma unroll
  for (int g = 0; g < G4; g++){ L[g] *= INV16; m[g] = wred_max(L[g]); }
  if ((t & 63) == 0)
    #pragma unroll
    for (int g = 0; g < G4; g++) redA[g][t >> 6] = m[g];
  __syncthreads();
  #pragma unroll
  for (int g = 0; g < G4; g++){
    m[g] = fmaxf(fmaxf(redA[g][0], redA[g][1]), fmaxf(redA[g][2], redA[g][3]));
    e[g] = __expf(L[g] - m[g]);
    s[g] = wred_sum(e[g]);
  }
  if ((t & 63) == 0)
    #pragma unroll
    for (int g = 0; g < G4; g++) redB2[g][t >> 6] = s[g];
  __syncthreads();
  #pragma unroll
  for (int g = 0; g < G4; g++){
    float ss = redB2[g][0] + redB2[g][1] + redB2[g][2] + redB2[g][3];
    float w = e[g] / ss;
    cwl[g][t] = w;
    cw_ws[(n0+g)*C_ + t] = w;
  }
  __syncthreads();
  // rcw (thread t = r < 64, wave 0)
  if (t < R_){
    float qd[G4] = {0.f,0.f,0.f,0.f}, md[G4] = {0.f,0.f,0.f,0.f};
    const float* rrow = rcb + t*D_;
    const float* mrow = MT_f32 + t*C_;
    #pragma unroll 4
    for (int k = 0; k < D_; k += 4){
      float4 wv = *(const float4*)(rrow + k);
      float4 mv = *(const float4*)(mrow + k);
      #pragma unroll
      for (int g = 0; g < G4; g++){
        qd[g] += qp[g][k]*wv.x + qp[g][k+1]*wv.y + qp[g][k+2]*wv.z + qp[g][k+3]*wv.w;
        md[g] += cwl[g][k]*mv.x + cwl[g][k+1]*mv.y + cwl[g][k+2]*mv.z + cwl[g][k+3]*mv.w;
      }
    }
    #pragma unroll
    for (int g = 0; g < G4; g++){
      float Lr = (qd[g] - md[g]) * INV16;
      float mr = wred_max(Lr);
      float er = __expf(Lr - mr);
      float sr = wred_sum(er);
      rcw_ws[(n0+g)*R_ + t] = er / sr;
    }
  }
}

// ---------------- K2a: weights pass (3 barriers, no V) ------------------------
// block = (n, 64-s tile); 4 waves; wave w owns c-frags {w+4f}, rcb frags for
// s-quarter sj==w, and s-quarter [w*16,+16) for WM/comb.
__global__ __launch_bounds__(256) void k2a(const float* __restrict__ Kt,
    const ushortT* __restrict__ a1pk, const ushortT* __restrict__ mtpk,
    const float* __restrict__ cw_ws, const float* __restrict__ rcw_ws,
    const float* __restrict__ rlogit, float* __restrict__ comb_ws,
    float* __restrict__ out_ew)
{
  __shared__ __align__(16) ushortT KW[64*256];   // 32 KB: Ktile, then Wexp overlay
  __shared__ float redS[4][64], redW[4][64];

  int bx  = blockIdx.x;
  int n   = bx >> 2;
  int s0  = (bx & 3) * 64;
  int tid = threadIdx.x;
  int lane = tid & 63, w = tid >> 6;
  int l15 = lane & 15, l4 = lane >> 4;
  float gate  = 1.f / (1.f + __expf(-rlogit[0]));
  float inv1g = 1.f / (1.f + gate);

  const float* Kn = Kt + (size_t)n*S_*D_ + (size_t)s0*D_;

  // ---- stage K tile fp32 -> bf16 swz LDS ----
  #pragma unroll
  for (int j = 0; j < 8; j++){
    int ch = tid + j*256;
    int row = ch >> 5, blk = ch & 31;
    const float* src = Kn + row*D_ + blk*8;
    float4 a = *(const float4*)src;
    float4 b = *(const float4*)(src + 4);
    uint4 wv = {packbf(a.x,a.y), packbf(a.z,a.w), packbf(b.x,b.y), packbf(b.z,b.w)};
    *(uint4*)((char*)KW + swz(row, blk*16)) = wv;
  }
  __syncthreads();                                   // B1

  // ---- GEMM1: accC[4][4] (c-quarter x all s) + accR[4] (all r x s-quarter w) --
  const ushortT* a1b = a1pk + (size_t)lane*8;
  bf8 bnxC[4], bnxR[4];
  #pragma unroll
  for (int f = 0; f < 4; f++){
    bnxC[f] = *(const bf8*)(a1b + (size_t)((w + 4*f)*64)*8);
    bnxR[f] = *(const bf8*)(a1b + (size_t)((16 + f)*64)*8);
  }
  f4 accC[4][4]; f4 accR[4];
  #pragma unroll
  for (int f = 0; f < 4; f++){
    accR[f] = (f4)0.f;
    #pragma unroll
    for (int sj = 0; sj < 4; sj++) accC[f][sj] = (f4)0.f;
  }
  #pragma unroll
  for (int ks = 0; ks < 8; ks++){
    bf8 kf0 = *(const bf8*)((const char*)KW + swz(     l15, ks*64 + l4*16));
    bf8 kf1 = *(const bf8*)((const char*)KW + swz(16 + l15, ks*64 + l4*16));
    bf8 kf2 = *(const bf8*)((const char*)KW + swz(32 + l15, ks*64 + l4*16));
    bf8 kf3 = *(const bf8*)((const char*)KW + swz(48 + l15, ks*64 + l4*16));
    bf8 kfw = *(const bf8*)((const char*)KW + swz(w*16 + l15, ks*64 + l4*16));
    #pragma unroll
    for (int f = 0; f < 4; f++){
      bf8 aC = bnxC[f], aR = bnxR[f];
      if (ks < 7){
        bnxC[f] = *(const bf8*)(a1b + (size_t)(((ks+1)*20 + w + 4*f)*64)*8);
        bnxR[f] = *(const bf8*)(a1b + (size_t)(((ks+1)*20 + 16 + f)*64)*8);
      }
      accC[f][0] = __builtin_amdgcn_mfma_f32_16x16x32_bf16(aC, kf0, accC[f][0], 0, 0, 0);
      accC[f][1] = __builtin_amdgcn_mfma_f32_16x16x32_bf16(aC, kf1, accC[f][1], 0, 0, 0);
      accC[f][2] = __builtin_amdgcn_mfma_f32_16x16x32_bf16(aC, kf2, accC[f][2], 0, 0, 0);
      accC[f][3] = __builtin_amdgcn_mfma_f32_16x16x32_bf16(aC, kf3, accC[f][3], 0, 0, 0);
      accR[f]    = __builtin_amdgcn_mfma_f32_16x16x32_bf16(aR, kfw, accR[f],    0, 0, 0);
    }
  }

  // ---- softmax-c partials (exp in place, unnormalized) ----
  float4 cwv[4];
  #pragma unroll
  for (int f = 0; f < 4; f++)
    cwv[f] = *(const float4*)(cw_ws + n*C_ + (w + 4*f)*16 + l4*4);
  float se[4] = {0,0,0,0}, sb[4] = {0,0,0,0};
  #pragma unroll
  for (int f = 0; f < 4; f++)
    #pragma unroll
    for (int sj = 0; sj < 4; sj++){
      float e0 = __expf(accC[f][sj][0] * INV16);
      float e1 = __expf(accC[f][sj][1] * INV16);
      float e2 = __expf(accC[f][sj][2] * INV16);
      float e3 = __expf(accC[f][sj][3] * INV16);
      accC[f][sj][0] = e0; accC[f][sj][1] = e1;
      accC[f][sj][2] = e2; accC[f][sj][3] = e3;
      se[sj] += (e0 + e1) + (e2 + e3);
      sb[sj] += e0*cwv[f].x + e1*cwv[f].y + e2*cwv[f].z + e3*cwv[f].w;
    }
  #pragma unroll
  for (int sj = 0; sj < 4; sj++){
    se[sj] += __shfl_xor(se[sj], 16); se[sj] += __shfl_xor(se[sj], 32);
    sb[sj] += __shfl_xor(sb[sj], 16); sb[sj] += __shfl_xor(sb[sj], 32);
  }
  if (l4 == 0){
    #pragma unroll
    for (int sj = 0; sj < 4; sj++){
      redS[w][sj*16 + l15] = se[sj];
      redW[w][sj*16 + l15] = sb[sj];
    }
  }
  __syncthreads();                                   // B2 (K reads done)

  float bw_q, rcp_q;
  {
    int sq = w*16 + l15;
    float sS = redS[0][sq] + redS[1][sq] + redS[2][sq] + redS[3][sq];
    float sW = redW[0][sq] + redW[1][sq] + redW[2][sq] + redW[3][sq];
    bw_q  = sW / sS;
    rcp_q = 1.f / sS;
  }
  // ---- Wexp (unnormalized, bf16) overlays Ktile ----
  #pragma unroll
  for (int f = 0; f < 4; f++){
    int cbyte = ((w + 4*f)*16 + l4*4) * 2;
    #pragma unroll
    for (int sj = 0; sj < 4; sj++){
      int s_ = sj*16 + l15;
      *(uint32*)((char*)KW + swz(s_, cbyte))     = packbf(accC[f][sj][0], accC[f][sj][1]);
      *(uint32*)((char*)KW + swz(s_, cbyte + 4)) = packbf(accC[f][sj][2], accC[f][sj][3]);
    }
  }
  __syncthreads();                                   // B3

  // ---- WM: MT(64 r) x Wexp[s-quarter w]^T -> wm[4]; MT streamed from L2 -----
  const ushortT* mtb = mtpk + (size_t)lane*8;
  bf8 mnx[4];
  #pragma unroll
  for (int fr = 0; fr < 4; fr++)
    mnx[fr] = *(const bf8*)(mtb + (size_t)(fr*64)*8);
  f4 wm[4];
  #pragma unroll
  for (int fr = 0; fr < 4; fr++) wm[fr] = (f4)0.f;
  #pragma unroll
  for (int ks = 0; ks < 8; ks++){
    bf8 wb = *(const bf8*)((const char*)KW + swz(w*16 + l15, ks*64 + l4*16));
    #pragma unroll
    for (int fr = 0; fr < 4; fr++){
      bf8 a = mnx[fr];
      if (ks < 7) mnx[fr] = *(const bf8*)(mtb + (size_t)(((ks+1)*4 + fr)*64)*8);
      wm[fr] = __builtin_amdgcn_mfma_f32_16x16x32_bf16(a, wb, wm[fr], 0, 0, 0);
    }
  }

  // ---- r-softmax (wave-local): l3 = (accR - wm*rcp_q)/16 ----
  float4 rcwv[4];
  #pragma unroll
  for (int fr = 0; fr < 4; fr++)
    rcwv[fr] = *(const float4*)(rcw_ws + n*R_ + fr*16 + l4*4);
  float se3 = 0.f, sc3 = 0.f;
  #pragma unroll
  for (int fr = 0; fr < 4; fr++){
    float e0 = __expf((accR[fr][0] - wm[fr][0]*rcp_q) * INV16);
    float e1 = __expf((accR[fr][1] - wm[fr][1]*rcp_q) * INV16);
    float e2 = __expf((accR[fr][2] - wm[fr][2]*rcp_q) * INV16);
    float e3 = __expf((accR[fr][3] - wm[fr][3]*rcp_q) * INV16);
    se3 += (e0 + e1) + (e2 + e3);
    sc3 += e0*rcwv[fr].x + e1*rcwv[fr].y + e2*rcwv[fr].z + e3*rcwv[fr].w;
  }
  se3 += __shfl_xor(se3, 16); se3 += __shfl_xor(se3, 32);
  sc3 += __shfl_xor(sc3, 16); sc3 += __shfl_xor(sc3, 32);
  float comb = bw_q + gate * (sc3 / se3);
  if (l4 == 0){
    int sabs = n*S_ + s0 + w*16 + l15;
    out_ew[sabs]  = comb * inv1g;
    comb_ws[sabs] = comb;
  }
}

// ---------------- K2b: summary streaming pass (HBM-bound) ---------------------
__global__ __launch_bounds__(256) void k2b(const float* __restrict__ Vt,
    const float* __restrict__ comb_ws, float* __restrict__ sum_ws)
{
  __shared__ float cl[S_];
  __shared__ float4 part[4][64];
  int n = blockIdx.x, tid = threadIdx.x;
  int lane = tid & 63, w = tid >> 6;
  cl[tid] = comb_ws[n*S_ + tid];
  __syncthreads();
  const float* Vn = Vt + (size_t)n*S_*D_ + (size_t)(w*64)*D_ + lane*4;
  float4 a0 = {0,0,0,0}, a1 = {0,0,0,0};
  #pragma unroll 8
  for (int j = 0; j < 64; j += 2){
    float4 v0 = *(const float4*)(Vn + (size_t)j*D_);
    float4 v1 = *(const float4*)(Vn + (size_t)(j+1)*D_);
    float c0 = cl[w*64 + j], c1 = cl[w*64 + j + 1];
    a0.x = fmaf(c0, v0.x, a0.x); a0.y = fmaf(c0, v0.y, a0.y);
    a0.z = fmaf(c0, v0.z, a0.z); a0.w = fmaf(c0, v0.w, a0.w);
    a1.x = fmaf(c1, v1.x, a1.x); a1.y = fmaf(c1, v1.y, a1.y);
    a1.z = fmaf(c1, v1.z, a1.z); a1.w = fmaf(c1, v1.w, a1.w);
  }
  float4 acc = {a0.x+a1.x, a0.y+a1.y, a0.z+a1.z, a0.w+a1.w};
  part[w][lane] = acc;
  __syncthreads();
  if (tid < 64){
    float4 p0 = part[0][tid], p1 = part[1][tid], p2 = part[2][tid], p3 = part[3][tid];
    float4 r = {p0.x+p1.x+p2.x+p3.x, p0.y+p1.y+p2.y+p3.y,
                p0.z+p1.z+p2.z+p3.z, p0.w+p1.w+p2.w+p3.w};
    *(float4*)(sum_ws + (size_t)n*D_ + tid*4) = r;
  }
}

// ---------------- K3: readout GEMM (MFMA, bf16) --------------------------------
__global__ __launch_bounds__(256) void k3(const float* __restrict__ sum_ws,
    const ushortT* __restrict__ Wcr_bf, const float* __restrict__ bc,
    const float* __restrict__ br, float* __restrict__ out)
{
  __shared__ __align__(16) ushortT Stile[64*256];
  int bx = blockIdx.x;
  int ot = bx >> 4;
  int nt = bx & 15;
  int tid = threadIdx.x;
  int lane = tid & 63, wid = tid >> 6;
  int l15 = lane & 15, l4 = lane >> 4;

  const float* Sp = sum_ws + (size_t)nt*64*D_;
  #pragma unroll
  for (int j = 0; j < 8; j++){
    int ch = tid + j*256;
    int row = ch >> 5, blk = ch & 31;
    const float* src = Sp + row*D_ + blk*8;
    float4 a = *(const float4*)src;
    float4 b = *(const float4*)(src + 4);
    uint4 wv = {packbf(a.x,a.y), packbf(a.z,a.w), packbf(b.x,b.y), packbf(b.z,b.w)};
    *(uint4*)((char*)Stile + swz(row, blk*16)) = wv;
  }
  __syncthreads();

  int o0 = ot*64 + wid*16;
  const ushortT* Ap = Wcr_bf + (size_t)(o0 + l15)*D_ + l4*8;
  f4 acc[4];
  #pragma unroll
  for (int j = 0; j < 4; j++) acc[j] = (f4)0.f;
  #pragma unroll
  for (int k = 0; k < 8; k++){
    bf8 a = *(const bf8*)(Ap + k*32);
    #pragma unroll
    for (int nj = 0; nj < 4; nj++){
      bf8 b = *(const bf8*)((const char*)Stile + swz(nj*16 + l15, k*64 + l4*16));
      acc[nj] = __builtin_amdgcn_mfma_f32_16x16x32_bf16(a, b, acc[nj], 0, 0, 0);
    }
  }
  int obase = o0 + l4*4;
  if (obase < 1256){
    float4 bias;
    if (obase < CLS_) bias = *(const float4*)(bc + obase);
    else              bias = *(const float4*)(br + (obase - CLS_));
    #pragma unroll
    for (int nj = 0; nj < 4; nj++){
      int nn = nt*64 + nj*16 + l15;
      float4 v = {acc[nj][0]+bias.x, acc[nj][1]+bias.y, acc[nj][2]+bias.z, acc[nj][3]+bias.w};
      if (obase < CLS_) *(float4*)(out + (size_t)nn*CLS_ + obase) = v;
      else              *(float4*)(out + (size_t)N_*CLS_ + (size_t)nn*D_ + (obase - CLS_)) = v;
    }
  }
}

extern "C" void kernel_launch(void* const* d_in, const int* in_sizes, int n_in,
                              void* d_out, int out_size, void* d_ws, size_t ws_size,
                              hipStream_t stream)
{
  const float* q    = (const float*)d_in[0];
  const float* Kt   = (const float*)d_in[1];
  const float* Vt   = (const float*)d_in[2];
  const float* cb   = (const float*)d_in[3];
  const float* rcb  = (const float*)d_in[4];
  const float* Wq   = (const float*)d_in[5];
  const float* rlg  = (const float*)d_in[6];
  const float* Wc   = (const float*)d_in[7];
  const float* bc   = (const float*)d_in[8];
  const float* Wr   = (const float*)d_in[9];
  const float* br   = (const float*)d_in[10];
  float* out = (float*)d_out;
  float* ws  = (float*)d_ws;

  float* cw_ws   = ws;                          // N*C
  float* rcw_ws  = ws + 262144;                 // N*R
  float* sum_ws  = ws + 327680;                 // N*D
  float* comb_ws = ws + 589824;                 // N*S
  float* MT_f32  = ws + 851968;                 // R*C
  ushortT* a1pk   = (ushortT*)(ws + 868352);    // 320*D frag-packed
  ushortT* mtpk   = a1pk + (C_ + R_)*D_;        // R*C frag-packed
  ushortT* Wcr_bf = mtpk + R_*C_;               // 1280*D (Wc ; Wr ; zero pad)

  float* out_logits = out;
  float* out_ew     = out + (size_t)N_*CLS_ + (size_t)N_*D_;

  k0 <<<128,   256, 0, stream>>>(cb, rcb, Wc, Wr, a1pk, Wcr_bf, MT_f32, mtpk);
  k1 <<<N_/G4, 256, 0, stream>>>(q, cb, rcb, Wq, MT_f32, cw_ws, rcw_ws);
  k2a<<<N_*4,  256, 0, stream>>>(Kt, a1pk, mtpk, cw_ws, rcw_ws, rlg, comb_ws, out_ew);
  k2b<<<N_,    256, 0, stream>>>(Vt, comb_ws, sum_ws);
  k3 <<<320,   256, 0, stream>>>(sum_ws, Wcr_bf, bc, br, out_logits);
}